// Round 13
// baseline (266.752 us; speedup 1.0000x reference)
//
#include <hip/hip_runtime.h>

#define T_SEQ 2048
#define NB 4
#define NH 16
#define HD 64
#define CDIM 1024
#define MROWS (NB * T_SEQ)  // 8192

typedef __attribute__((ext_vector_type(8))) short short8;
typedef __attribute__((ext_vector_type(4))) float floatx4;

static __device__ __forceinline__ unsigned short f2bf(float f) {
  union { float f; unsigned int i; } c; c.f = f;
  return (unsigned short)((c.i + 0x7FFFu + ((c.i >> 16) & 1u)) >> 16);
}
static __device__ __forceinline__ unsigned short f2bf_trunc(float f) {
  union { float f; unsigned int i; } c; c.f = f;
  return (unsigned short)(c.i >> 16);
}

// async 16B/lane global->LDS (emits global_load_lds_dwordx4).
static __device__ __forceinline__ void gl2lds16(const void* g, void* l) {
  __builtin_amdgcn_global_load_lds(
      (const __attribute__((address_space(1))) unsigned int*)g,
      (__attribute__((address_space(3))) unsigned int*)l, 16, 0, 0);
}

// ---------------- fused fp32 -> bf16 cast (x | Wqkv | Wproj) ----------------
#define X4 (MROWS * CDIM / 4)            // 2097152
#define WQ4 (3 * CDIM * CDIM / 4)        // 786432
#define WP4 (CDIM * CDIM / 4)            // 262144
__global__ __launch_bounds__(256) void cast3_bf16(const float* __restrict__ x,
                                                  const float* __restrict__ wq,
                                                  const float* __restrict__ wp,
                                                  unsigned short* __restrict__ out) {
  const int i = blockIdx.x * 256 + threadIdx.x;
  const float* src; int off;
  if (i < X4) { src = x; off = i; }
  else if (i < X4 + WQ4) { src = wq; off = i - X4; }
  else { src = wp; off = i - X4 - WQ4; }
  const float4 v = ((const float4*)src)[off];
  ushort4 o;
  o.x = f2bf(v.x); o.y = f2bf(v.y); o.z = f2bf(v.z); o.w = f2bf(v.w);
  ((ushort4*)out)[i] = o;
}

#define Q_PRESCALE 0.18033688f   // 1/sqrt(64) * log2(e)

// ========== 256x256 / BK=64, 8-wave, 4-phase QKV GEMM (R6, unchanged) ======
#define QNT (CDIM / 64)   // 16 K-tiles

__global__ __launch_bounds__(512, 2) void gemm_bf16_qkv256(
    const unsigned short* __restrict__ A,   // [M,K] bf16 (x)
    const unsigned short* __restrict__ B,   // [N,K] bf16 (Wqkv)
    unsigned short* __restrict__ Oq,
    unsigned short* __restrict__ Ok,
    unsigned short* __restrict__ Ovt,       // [B,H,D,T]
    const int K)
{
  __shared__ __align__(16) unsigned short As[2][2][128 * 64];  // [buf][half]
  __shared__ __align__(16) unsigned short Bs[2][2][128 * 64];
  const int tid = threadIdx.x;
  const int w = tid >> 6, l = tid & 63;
  const int quad = l >> 4, l15 = l & 15;
  const int wr = w >> 2, wc = w & 3;               // 2M x 4N wave grid
  // XCD-aware bijective swizzle: 384 blocks, 8 XCDs, 48 blocks/XCD chunk.
  const int lin = blockIdx.y * 12 + blockIdx.x;
  const int swz = (lin & 7) * 48 + (lin >> 3);
  const int m0 = (swz / 12) * 256, n0 = (swz % 12) * 256;

  const int lrow = l >> 3;
  const int lch = ((l & 7) ^ lrow) * 8;
  const unsigned short* Ag = A + (size_t)(m0 + w * 16 + lrow) * K + lch;
  const unsigned short* Bg = B + (size_t)(n0 + w * 16 + lrow) * K + lch;
  const int ld0 = w * 1024, ld1 = w * 1024 + 512;  // stripe dests (shorts)
  const size_t rsk = (size_t)8 * K;                // +8 rows

#define STAGE_A(buf, h, kof) do { \
    gl2lds16(Ag + (size_t)(h) * 128 * K + (kof), &As[buf][h][ld0]); \
    gl2lds16(Ag + (size_t)(h) * 128 * K + rsk + (kof), &As[buf][h][ld1]); } while (0)
#define STAGE_B(buf, h, kof) do { \
    gl2lds16(Bg + (size_t)(h) * 128 * K + (kof), &Bs[buf][h][ld0]); \
    gl2lds16(Bg + (size_t)(h) * 128 * K + rsk + (kof), &Bs[buf][h][ld1]); } while (0)

  const int sw7 = l15 & 7;
  const int co0 = (quad ^ sw7) * 8;
  const int co1 = co0 ^ 32;                        // ks=1: chunk ^ 4
  const int fb = l15 * 64;
  const unsigned short* Aw0 = &As[0][wr][0];
  const unsigned short* Aw1 = &As[1][wr][0];
  const unsigned short* Bw0 = &Bs[0][wc >> 1][(wc & 1) * 4096];
  const unsigned short* Bw1 = &Bs[1][wc >> 1][(wc & 1) * 4096];

  floatx4 acc[8][4];
#pragma unroll
  for (int mi = 0; mi < 8; ++mi)
#pragma unroll
    for (int ni = 0; ni < 4; ++ni) acc[mi][ni] = (floatx4){0.f, 0.f, 0.f, 0.f};

  // prologue: tile0 complete -> buf0; B0,A0 of tile1 -> buf1; leave 2 in flight
  STAGE_A(0, 0, 0); STAGE_A(0, 1, 0); STAGE_B(0, 0, 0); STAGE_B(0, 1, 0);
  STAGE_B(1, 0, 64); STAGE_A(1, 0, 64);
  asm volatile("s_waitcnt vmcnt(4)" ::: "memory");   // tile0 landed
  __builtin_amdgcn_s_barrier();

#pragma unroll 1
  for (int j = 0; j < QNT; ++j) {
    const int cur = j & 1, nxt = cur ^ 1;
    const unsigned short* Ac = cur ? Aw1 : Aw0;
    const unsigned short* Bc = cur ? Bw1 : Bw0;
    const int kA = (j + 1) * 64, kC = (j + 2) * 64;
    short8 aF[2][4], bL[2][2], bH[2][2];

    // ---- phase A: quadrant (mi 0-3) x (ni 0-1); stage A1(j+1)->nxt ----
#pragma unroll
    for (int mi = 0; mi < 4; ++mi) {
      aF[0][mi] = *(const short8*)(Ac + mi * 1024 + fb + co0);
      aF[1][mi] = *(const short8*)(Ac + mi * 1024 + fb + co1);
    }
#pragma unroll
    for (int ni = 0; ni < 2; ++ni) {
      bL[0][ni] = *(const short8*)(Bc + ni * 1024 + fb + co0);
      bL[1][ni] = *(const short8*)(Bc + ni * 1024 + fb + co1);
    }
    if (j + 1 < QNT) STAGE_A(nxt, 1, kA);
    __builtin_amdgcn_s_barrier();
    asm volatile("s_waitcnt lgkmcnt(0)" ::: "memory");
    __builtin_amdgcn_s_setprio(1);
#pragma unroll
    for (int ks = 0; ks < 2; ++ks)
#pragma unroll
      for (int mi = 0; mi < 4; ++mi)
#pragma unroll
        for (int ni = 0; ni < 2; ++ni)
          acc[mi][ni] = __builtin_amdgcn_mfma_f32_16x16x32_bf16(
              bL[ks][ni], aF[ks][mi], acc[mi][ni], 0, 0, 0);
    __builtin_amdgcn_s_setprio(0);
    __builtin_amdgcn_s_barrier();

    // ---- phase B: (mi 0-3) x (ni 2-3); stage B1(j+1)->nxt ----
#pragma unroll
    for (int ni = 0; ni < 2; ++ni) {
      bH[0][ni] = *(const short8*)(Bc + (ni + 2) * 1024 + fb + co0);
      bH[1][ni] = *(const short8*)(Bc + (ni + 2) * 1024 + fb + co1);
    }
    if (j + 1 < QNT) STAGE_B(nxt, 1, kA);
    __builtin_amdgcn_s_barrier();
    asm volatile("s_waitcnt lgkmcnt(0)" ::: "memory");
    __builtin_amdgcn_s_setprio(1);
#pragma unroll
    for (int ks = 0; ks < 2; ++ks)
#pragma unroll
      for (int mi = 0; mi < 4; ++mi)
#pragma unroll
        for (int ni = 0; ni < 2; ++ni)
          acc[mi][ni + 2] = __builtin_amdgcn_mfma_f32_16x16x32_bf16(
              bH[ks][ni], aF[ks][mi], acc[mi][ni + 2], 0, 0, 0);
    __builtin_amdgcn_s_setprio(0);
    __builtin_amdgcn_s_barrier();

    // ---- phase C: (mi 4-7) x (ni 0-1); stage B0(j+2)->cur (dead after B) --
#pragma unroll
    for (int mi = 0; mi < 4; ++mi) {
      aF[0][mi] = *(const short8*)(Ac + (mi + 4) * 1024 + fb + co0);
      aF[1][mi] = *(const short8*)(Ac + (mi + 4) * 1024 + fb + co1);
    }
    if (j + 2 < QNT) STAGE_B(cur, 0, kC);
    __builtin_amdgcn_s_barrier();
    asm volatile("s_waitcnt lgkmcnt(0)" ::: "memory");
    __builtin_amdgcn_s_setprio(1);
#pragma unroll
    for (int ks = 0; ks < 2; ++ks)
#pragma unroll
      for (int mi = 0; mi < 4; ++mi)
#pragma unroll
        for (int ni = 0; ni < 2; ++ni)
          acc[mi + 4][ni] = __builtin_amdgcn_mfma_f32_16x16x32_bf16(
              bL[ks][ni], aF[ks][mi], acc[mi + 4][ni], 0, 0, 0);
    __builtin_amdgcn_s_setprio(0);
    __builtin_amdgcn_s_barrier();

    // ---- phase D: (mi 4-7) x (ni 2-3); stage A0(j+2)->cur (dead after C);
    //      counted vmcnt: keep 2 half-tiles (4 loads) in flight ----
    if (j + 2 < QNT) {
      STAGE_A(cur, 0, kC);
      asm volatile("s_waitcnt vmcnt(4)" ::: "memory");  // tile j+1 landed
    } else {
      asm volatile("s_waitcnt vmcnt(0)" ::: "memory");  // tail drain
    }
    __builtin_amdgcn_s_barrier();
    __builtin_amdgcn_s_setprio(1);
#pragma unroll
    for (int ks = 0; ks < 2; ++ks)
#pragma unroll
      for (int mi = 0; mi < 4; ++mi)
#pragma unroll
        for (int ni = 0; ni < 2; ++ni)
          acc[mi + 4][ni + 2] = __builtin_amdgcn_mfma_f32_16x16x32_bf16(
              bH[ks][ni], aF[ks][mi], acc[mi + 4][ni + 2], 0, 0, 0);
    __builtin_amdgcn_s_setprio(0);
    __builtin_amdgcn_s_barrier();
  }
#undef STAGE_A
#undef STAGE_B

  // epilogue: m = m0+wr*128+mi*16+l15, n = n0+wc*64+ni*16+quad*4+r
  const int which = n0 >> 10;                      // block-uniform: q/k/v
  if (which < 2) {
    unsigned short* dst = (which == 0) ? Oq : Ok;
    const float sc = (which == 0) ? Q_PRESCALE : 1.0f;
#pragma unroll
    for (int ni = 0; ni < 4; ++ni) {
      const int n = n0 + wc * 64 + ni * 16 + quad * 4;
      const int h = (n >> 6) & (NH - 1), d = n & (HD - 1);
#pragma unroll
      for (int mi = 0; mi < 8; ++mi) {
        const int m = m0 + wr * 128 + mi * 16 + l15;
        const int b = m >> 11, t = m & (T_SEQ - 1);
        ushort4 pk;
        pk.x = f2bf(acc[mi][ni][0] * sc); pk.y = f2bf(acc[mi][ni][1] * sc);
        pk.z = f2bf(acc[mi][ni][2] * sc); pk.w = f2bf(acc[mi][ni][3] * sc);
        *(ushort4*)(dst + (((size_t)(b * NH + h) * T_SEQ + t) << 6) + d) = pk;
      }
    }
  } else {
#pragma unroll
    for (int ni = 0; ni < 4; ++ni) {
      const int nb = n0 + wc * 64 + ni * 16 + quad * 4;
      const int h = (nb >> 6) & (NH - 1);
#pragma unroll
      for (int mi = 0; mi < 8; ++mi) {
        const int m = m0 + wr * 128 + mi * 16 + l15;
        const int b = m >> 11, t = m & (T_SEQ - 1);
#pragma unroll
        for (int r = 0; r < 4; ++r) {
          const int d = (nb + r) & (HD - 1);
          Ovt[((size_t)((b * NH + h) * HD + d) << 11) + t] = f2bf(acc[mi][ni][r]);
        }
      }
    }
  }
}

// ===== proj v3: 128x128 / BK=64, 4-wave, B-OPERAND FROM GLOBAL (no B LDS) ==
// Three LDS-staged proj schedules all measured ~equal (~75us residual) ->
// schedule isn't the constraint; the LDS/staging machinery per MFMA is.
// Wproj = 2 MB = L2-resident after first sweep/XCD: load B fragments
// DIRECTLY global->regs (8 x global_load_dwordx4 per wave per K-tile,
// double-buffered reg sets bA/bB, prefetched 1 K-tile ahead; compiler
// auto-waits the reg loads). Halves LDS reads (16->8/wave/kt), halves DMA
// (8->4 gl2lds16/thread/kt), LDS 80->32 KiB. 1 barrier/K-tile kept.
// vmcnt ledger: issue A(j+1)x4 THEN B(j+1)x8; end-of-tile vmcnt(8) retires
// exactly A(j+1) (in-order), leaves B(j+1) in flight for compiler to wait.
// WAR on As[nxt]: readers lgkm0'd before previous barrier. Tail vmcnt(0).
// Loop unrolled x2 with NAMED reg sets (no runtime-indexed reg arrays).
// Grid (8,64)=512 blocks = 1 round @2 blocks/CU; bijective XCD swizzle.
__global__ __launch_bounds__(256, 2) void gemm_bf16_projBG(
    const unsigned short* __restrict__ A,   // [M,K] bf16 (attn out)
    const unsigned short* __restrict__ B,   // [N,K] bf16 (Wproj)
    float* __restrict__ O,                  // [M,N] fp32
    const int K)
{
  __shared__ __align__(16) unsigned short As[2][128 * 64];  // 32 KiB
  const int tid = threadIdx.x;
  const int w = tid >> 6, l = tid & 63;
  const int quad = l >> 4, l15 = l & 15;
  const int wr = w >> 1, wc = w & 1;               // 2M x 2N wave grid
  const int lin = blockIdx.y * 8 + blockIdx.x;
  const int swz = (lin & 7) * 64 + (lin >> 3);     // bijective, 512%8==0
  const int m0 = (swz >> 3) * 128, n0 = (swz & 7) * 128;

  // A staging: 256 threads cover one 32-row chunk (4 KiB) per gl2lds16.
  const int st_row = tid >> 3;                     // 0..31
  const int st_sch = ((tid & 7) ^ (st_row & 7)) * 8;
  const unsigned short* Ast = A + (size_t)(m0 + st_row) * K + st_sch;
  const int dst8 = tid * 8;

#define PSTG_A(buf, kof) do { \
    gl2lds16(Ast + (kof), &As[buf][dst8]); \
    gl2lds16(Ast + (size_t)32 * K + (kof), &As[buf][2048 + dst8]); \
    gl2lds16(Ast + (size_t)64 * K + (kof), &As[buf][4096 + dst8]); \
    gl2lds16(Ast + (size_t)96 * K + (kof), &As[buf][6144 + dst8]); } while (0)

  // A fragment reads: row = wr*64 + mi*16 + l15; chunk = (ks*4+quad)^(l15&7)
  const int sw7 = l15 & 7;
  const int co0 = (quad ^ sw7) * 8;
  const int co1 = co0 ^ 32;
  const unsigned short* Aw0 = &As[0][wr * 4096 + l15 * 64];
  const unsigned short* Aw1 = &As[1][wr * 4096 + l15 * 64];

  // B fragments from GLOBAL: row n = n0 + wc*64 + ni*16 + l15,
  // k = j*64 + ks*32 + quad*8 (8 bf16 per load).
  const unsigned short* Bg2 = B + (size_t)(n0 + wc * 64 + l15) * K + quad * 8;

#define LOADB(dst, J) do { \
    _Pragma("unroll") \
    for (int ni = 0; ni < 4; ++ni) { \
      dst[0][ni] = *(const short8*)(Bg2 + (size_t)(ni * 16) * K + (J) * 64); \
      dst[1][ni] = *(const short8*)(Bg2 + (size_t)(ni * 16) * K + (J) * 64 + 32); \
    } } while (0)

  floatx4 acc[4][4];
#pragma unroll
  for (int mi = 0; mi < 4; ++mi)
#pragma unroll
    for (int ni = 0; ni < 4; ++ni) acc[mi][ni] = (floatx4){0.f, 0.f, 0.f, 0.f};

  short8 bA[2][4], bB[2][4];

  // prologue: A(0)->As0 (4 DMA) + B(0)->bA regs (8 loads); drain; barrier.
  PSTG_A(0, 0);
  LOADB(bA, 0);
  asm volatile("s_waitcnt vmcnt(0)" ::: "memory");
  __builtin_amdgcn_s_barrier();

  // One K-tile: read aF; prefetch A(j+1) lds + B(j+1) regs; 32 MFMA;
  // counted vmcnt(8) (A landed, B rides); barrier.
#define KTILE(ACUR, ANXT, BCUR, BNXT, J) do { \
    short8 aF[2][4]; \
    _Pragma("unroll") \
    for (int mi = 0; mi < 4; ++mi) { \
      aF[0][mi] = *(const short8*)((ACUR) + mi * 1024 + co0); \
      aF[1][mi] = *(const short8*)((ACUR) + mi * 1024 + co1); \
    } \
    if ((J) + 1 < QNT) { PSTG_A(ANXT, ((J) + 1) * 64); LOADB(BNXT, (J) + 1); } \
    asm volatile("s_waitcnt lgkmcnt(0)" ::: "memory"); \
    __builtin_amdgcn_s_setprio(1); \
    _Pragma("unroll") \
    for (int ks = 0; ks < 2; ++ks) \
      _Pragma("unroll") \
      for (int mi = 0; mi < 4; ++mi) \
        _Pragma("unroll") \
        for (int ni = 0; ni < 4; ++ni) \
          acc[mi][ni] = __builtin_amdgcn_mfma_f32_16x16x32_bf16( \
              BCUR[ks][ni], aF[ks][mi], acc[mi][ni], 0, 0, 0); \
    __builtin_amdgcn_s_setprio(0); \
    if ((J) + 1 < QNT) asm volatile("s_waitcnt vmcnt(8)" ::: "memory"); \
    else               asm volatile("s_waitcnt vmcnt(0)" ::: "memory"); \
    __builtin_amdgcn_s_barrier(); \
  } while (0)

#pragma unroll 1
  for (int jj = 0; jj < QNT; jj += 2) {
    KTILE(Aw0, 1, bA, bB, jj);
    KTILE(Aw1, 0, bB, bA, jj + 1);
  }
#undef KTILE
#undef LOADB
#undef PSTG_A

  // epilogue: m = m0+wr*64+mi*16+l15, n = n0+wc*64+ni*16+quad*4+r (fp32x4)
#pragma unroll
  for (int ni = 0; ni < 4; ++ni) {
    const int n = n0 + wc * 64 + ni * 16 + quad * 4;
#pragma unroll
    for (int mi = 0; mi < 4; ++mi) {
      const int m = m0 + wr * 64 + mi * 16 + l15;
      *(float4*)(O + (size_t)m * CDIM + n) =
          make_float4(acc[mi][ni][0], acc[mi][ni][1], acc[mi][ni][2], acc[mi][ni][3]);
    }
  }
}

// ======== Flash attention v6 (best measured; v7/v8 both worse) ====
#define TK 64
#define PTP 72     // Pt pitch (2-way max on writes = free)

__global__ __launch_bounds__(512) void attn_mfma(
    const unsigned short* __restrict__ Q,
    const unsigned short* __restrict__ K,
    const unsigned short* __restrict__ Vt,
    unsigned short* __restrict__ O)
{
  __shared__ unsigned short Ks[2][TK * HD];     // swizzled, 2x8 KB
  __shared__ unsigned short Vts[2][HD * TK];    // swizzled, 2x8 KB
  __shared__ unsigned short Pt[8][16 * PTP];    // per-wave P^T (18.4 KB)
  const int tid = threadIdx.x;
  const int w = tid >> 6, l = tid & 63;         // 8 waves
  const int quad = l >> 4, l15 = l & 15;
  const int drow = 8 * w + (l >> 3);
  const int dch = ((l & 7) ^ (l >> 3)) * 8;     // XOR-swizzled source chunk
  const int sw7 = l15 & 7;

  const int bh = blockIdx.x & 63;
  const int pp = blockIdx.x >> 6;               // 0..7
  const int b = bh >> 4, h = bh & 15;
  const size_t hoff = (size_t)bh * T_SEQ * HD;
  const unsigned short* Qh = Q + hoff;
  const unsigned short* Kdma = K + hoff + (size_t)drow * HD + dch;
  const unsigned short* Vdma = Vt + hoff + ((size_t)drow << 11) + dch;
  const int wb = w * 512;                       // wave's LDS slice (ushorts)

  short8 ones;
#pragma unroll
  for (int j = 0; j < 8; ++j) ones[j] = (short)0x3F80;  // bf16 1.0

#pragma unroll 1
  for (int ii = 0; ii < 2; ++ii) {
    const int qtile = ii ? pp : (15 - pp);      // heavy first
    const int qw = qtile * 128 + w * 16;

    short8 qf[2];
    {
      const int qrow = qw + l15;
      qf[0] = *(const short8*)(Qh + (size_t)qrow * HD + quad * 8);
      qf[1] = *(const short8*)(Qh + (size_t)qrow * HD + 32 + quad * 8);
    }

    floatx4 Of[4];
#pragma unroll
    for (int dc = 0; dc < 4; ++dc) Of[dc] = (floatx4){0.f, 0.f, 0.f, 0.f};
    floatx4 lacc = (floatx4){0.f, 0.f, 0.f, 0.f};

    const int nkt = 2 * qtile + 2;
    __syncthreads();                  // (ii=1) prior reads of buf0 done
    gl2lds16(Kdma, &Ks[0][wb]);       // prologue: tile 0 -> buf0
    gl2lds16(Vdma, &Vts[0][wb]);

    for (int kt = 0; kt < nkt; ++kt) {
      const int kt0 = kt * TK;
      const int cur = kt & 1, nxt = 1 - cur;
      __syncthreads();                // drains DMA kt; buf[nxt] reads done
      if (kt + 1 < nkt) {             // DMA kt+1 overlaps compute of kt
        gl2lds16(Kdma + (size_t)(kt0 + TK) * HD, &Ks[nxt][wb]);
        gl2lds16(Vdma + kt0 + TK, &Vts[nxt][wb]);
      }

      if (qw + 15 >= kt0) {           // wave-uniform: skip fully-masked tiles
        // --- S^T = K Q^T ---
        floatx4 Sf[4];
#pragma unroll
        for (int cb = 0; cb < 4; ++cb) {
          Sf[cb] = (floatx4){0.f, 0.f, 0.f, 0.f};
          const int krow = cb * 16 + l15;
#pragma unroll
          for (int h2 = 0; h2 < 2; ++h2) {
            const int ch = (h2 * 4 + quad) ^ sw7;
            const short8 kf = *(const short8*)&Ks[cur][krow * 64 + ch * 8];
            Sf[cb] = __builtin_amdgcn_mfma_f32_16x16x32_bf16(kf, qf[h2], Sf[cb], 0, 0, 0);
          }
        }
        // --- p = exp2(s); lane's 16 values all for q = qw+l15 ---
        const bool full = (kt0 + 63 <= qw);
        const int q = qw + l15;
#pragma unroll
        for (int cb = 0; cb < 4; ++cb) {
          const int key0 = kt0 + cb * 16 + quad * 4;
          ushort4 pk;
          if (full) {
            pk.x = f2bf_trunc(exp2f(Sf[cb][0]));
            pk.y = f2bf_trunc(exp2f(Sf[cb][1]));
            pk.z = f2bf_trunc(exp2f(Sf[cb][2]));
            pk.w = f2bf_trunc(exp2f(Sf[cb][3]));
          } else {
            pk.x = (key0 + 0 > q) ? 0 : f2bf_trunc(exp2f(Sf[cb][0]));
            pk.y = (key0 + 1 > q) ? 0 : f2bf_trunc(exp2f(Sf[cb][1]));
            pk.z = (key0 + 2 > q) ? 0 : f2bf_trunc(exp2f(Sf[cb][2]));
            pk.w = (key0 + 3 > q) ? 0 : f2bf_trunc(exp2f(Sf[cb][3]));
          }
          *(ushort4*)&Pt[w][l15 * PTP + cb * 16 + quad * 4] = pk;
        }
        // --- O^T += V^T P^T ; l += 1^T P^T ---
#pragma unroll
        for (int kg = 0; kg < 2; ++kg) {
          const short8 ptf = *(const short8*)&Pt[w][l15 * PTP + kg * 32 + quad * 8];
          lacc = __builtin_amdgcn_mfma_f32_16x16x32_bf16(ones, ptf, lacc, 0, 0, 0);
#pragma unroll
          for (int dc = 0; dc < 4; ++dc) {
            const int vrow = dc * 16 + l15;
            const int ch = (kg * 4 + quad) ^ sw7;
            const short8 vf = *(const short8*)&Vts[cur][vrow * 64 + ch * 8];
            Of[dc] = __builtin_amdgcn_mfma_f32_16x16x32_bf16(vf, ptf, Of[dc], 0, 0, 0);
          }
        }
      }
    }

    // epilogue: lane owns token q = qw+l15; d = dc*16+quad*4+{0..3}
    const float inv = 1.f / lacc[0];
    const int q = qw + l15;
    unsigned short* orow = O + (size_t)(b * T_SEQ + q) * CDIM + h * HD + quad * 4;
#pragma unroll
    for (int dc = 0; dc < 4; ++dc) {
      ushort4 ov;
      ov.x = f2bf(Of[dc][0] * inv); ov.y = f2bf(Of[dc][1] * inv);
      ov.z = f2bf(Of[dc][2] * inv); ov.w = f2bf(Of[dc][3] * inv);
      *(ushort4*)(orow + dc * 16) = ov;
    }
  }
}

extern "C" void kernel_launch(void* const* d_in, const int* in_sizes, int n_in,
                              void* d_out, int out_size, void* d_ws, size_t ws_size,
                              hipStream_t stream) {
  const float* x     = (const float*)d_in[0];  // [B,T,C]
  const float* Wqkv  = (const float*)d_in[1];  // [3C,C]
  const float* Wproj = (const float*)d_in[2];  // [C,C]
  float* out = (float*)d_out;                  // [B,T,C] fp32

  const size_t XSZ = (size_t)MROWS * CDIM;          // 8388608
  const size_t WQSZ = (size_t)3 * CDIM * CDIM;      // 3145728
  const size_t WPSZ = (size_t)CDIM * CDIM;          // 1048576
  unsigned short* xb  = (unsigned short*)d_ws;      // bf16 x
  unsigned short* wqb = xb + XSZ;                   // bf16 Wqkv
  unsigned short* wpb = wqb + WQSZ;                 // bf16 Wproj
  unsigned short* qbuf = wpb + WPSZ;                // bf16 [B,H,T,D] (pre-scaled)
  unsigned short* kbuf = qbuf + XSZ;
  unsigned short* vtbuf = kbuf + XSZ;               // bf16 [B,H,D,T]
  unsigned short* abuf = vtbuf + XSZ;               // bf16 [B,T,C]

  // 0) fused casts to bf16 (xb|wqb|wpb contiguous)
  cast3_bf16<<<(X4 + WQ4 + WP4) / 256, 256, 0, stream>>>(x, Wqkv, Wproj, xb);

  // 1) QKV projection: R3 4-phase schedule + XCD swizzle
  dim3 g1(3 * CDIM / 256, MROWS / 256);   // (12,32)
  gemm_bf16_qkv256<<<g1, 512, 0, stream>>>(xb, wqb, qbuf, kbuf, vtbuf, CDIM);

  // 2) flash attention v6 (best measured)
  attn_mfma<<<512, 512, 0, stream>>>(qbuf, kbuf, vtbuf, abuf);

  // 3) output projection: B-from-global, 512 blocks = 1 round @2/CU
  dim3 g3(CDIM / 128, MROWS / 128);       // (8,64)
  gemm_bf16_projBG<<<g3, 256, 0, stream>>>(abuf, wpb, out, CDIM);
}

// Round 14
// 244.318 us; speedup vs baseline: 1.0918x; 1.0918x over previous
//
#include <hip/hip_runtime.h>

#define T_SEQ 2048
#define NB 4
#define NH 16
#define HD 64
#define CDIM 1024
#define MROWS (NB * T_SEQ)  // 8192

typedef __attribute__((ext_vector_type(8))) short short8;
typedef __attribute__((ext_vector_type(4))) float floatx4;

static __device__ __forceinline__ unsigned short f2bf(float f) {
  union { float f; unsigned int i; } c; c.f = f;
  return (unsigned short)((c.i + 0x7FFFu + ((c.i >> 16) & 1u)) >> 16);
}
static __device__ __forceinline__ unsigned short f2bf_trunc(float f) {
  union { float f; unsigned int i; } c; c.f = f;
  return (unsigned short)(c.i >> 16);
}

// async 16B/lane global->LDS (emits global_load_lds_dwordx4).
static __device__ __forceinline__ void gl2lds16(const void* g, void* l) {
  __builtin_amdgcn_global_load_lds(
      (const __attribute__((address_space(1))) unsigned int*)g,
      (__attribute__((address_space(3))) unsigned int*)l, 16, 0, 0);
}

// ---------------- fused fp32 -> bf16 cast (x | Wqkv | Wproj) ----------------
#define X4 (MROWS * CDIM / 4)            // 2097152
#define WQ4 (3 * CDIM * CDIM / 4)        // 786432
#define WP4 (CDIM * CDIM / 4)            // 262144
__global__ __launch_bounds__(256) void cast3_bf16(const float* __restrict__ x,
                                                  const float* __restrict__ wq,
                                                  const float* __restrict__ wp,
                                                  unsigned short* __restrict__ out) {
  const int i = blockIdx.x * 256 + threadIdx.x;
  const float* src; int off;
  if (i < X4) { src = x; off = i; }
  else if (i < X4 + WQ4) { src = wq; off = i - X4; }
  else { src = wp; off = i - X4 - WQ4; }
  const float4 v = ((const float4*)src)[off];
  ushort4 o;
  o.x = f2bf(v.x); o.y = f2bf(v.y); o.z = f2bf(v.z); o.w = f2bf(v.w);
  ((ushort4*)out)[i] = o;
}

#define Q_PRESCALE 0.18033688f   // 1/sqrt(64) * log2(e)

// ========== 256x256 / BK=64, 8-wave, 4-phase QKV GEMM (R6, unchanged) ======
#define QNT (CDIM / 64)   // 16 K-tiles

__global__ __launch_bounds__(512, 2) void gemm_bf16_qkv256(
    const unsigned short* __restrict__ A,   // [M,K] bf16 (x)
    const unsigned short* __restrict__ B,   // [N,K] bf16 (Wqkv)
    unsigned short* __restrict__ Oq,
    unsigned short* __restrict__ Ok,
    unsigned short* __restrict__ Ovt,       // [B,H,D,T]
    const int K)
{
  __shared__ __align__(16) unsigned short As[2][2][128 * 64];  // [buf][half]
  __shared__ __align__(16) unsigned short Bs[2][2][128 * 64];
  const int tid = threadIdx.x;
  const int w = tid >> 6, l = tid & 63;
  const int quad = l >> 4, l15 = l & 15;
  const int wr = w >> 2, wc = w & 3;               // 2M x 4N wave grid
  // XCD-aware bijective swizzle: 384 blocks, 8 XCDs, 48 blocks/XCD chunk.
  const int lin = blockIdx.y * 12 + blockIdx.x;
  const int swz = (lin & 7) * 48 + (lin >> 3);
  const int m0 = (swz / 12) * 256, n0 = (swz % 12) * 256;

  const int lrow = l >> 3;
  const int lch = ((l & 7) ^ lrow) * 8;
  const unsigned short* Ag = A + (size_t)(m0 + w * 16 + lrow) * K + lch;
  const unsigned short* Bg = B + (size_t)(n0 + w * 16 + lrow) * K + lch;
  const int ld0 = w * 1024, ld1 = w * 1024 + 512;  // stripe dests (shorts)
  const size_t rsk = (size_t)8 * K;                // +8 rows

#define STAGE_A(buf, h, kof) do { \
    gl2lds16(Ag + (size_t)(h) * 128 * K + (kof), &As[buf][h][ld0]); \
    gl2lds16(Ag + (size_t)(h) * 128 * K + rsk + (kof), &As[buf][h][ld1]); } while (0)
#define STAGE_B(buf, h, kof) do { \
    gl2lds16(Bg + (size_t)(h) * 128 * K + (kof), &Bs[buf][h][ld0]); \
    gl2lds16(Bg + (size_t)(h) * 128 * K + rsk + (kof), &Bs[buf][h][ld1]); } while (0)

  const int sw7 = l15 & 7;
  const int co0 = (quad ^ sw7) * 8;
  const int co1 = co0 ^ 32;                        // ks=1: chunk ^ 4
  const int fb = l15 * 64;
  const unsigned short* Aw0 = &As[0][wr][0];
  const unsigned short* Aw1 = &As[1][wr][0];
  const unsigned short* Bw0 = &Bs[0][wc >> 1][(wc & 1) * 4096];
  const unsigned short* Bw1 = &Bs[1][wc >> 1][(wc & 1) * 4096];

  floatx4 acc[8][4];
#pragma unroll
  for (int mi = 0; mi < 8; ++mi)
#pragma unroll
    for (int ni = 0; ni < 4; ++ni) acc[mi][ni] = (floatx4){0.f, 0.f, 0.f, 0.f};

  // prologue: tile0 complete -> buf0; B0,A0 of tile1 -> buf1; leave 2 in flight
  STAGE_A(0, 0, 0); STAGE_A(0, 1, 0); STAGE_B(0, 0, 0); STAGE_B(0, 1, 0);
  STAGE_B(1, 0, 64); STAGE_A(1, 0, 64);
  asm volatile("s_waitcnt vmcnt(4)" ::: "memory");   // tile0 landed
  __builtin_amdgcn_s_barrier();

#pragma unroll 1
  for (int j = 0; j < QNT; ++j) {
    const int cur = j & 1, nxt = cur ^ 1;
    const unsigned short* Ac = cur ? Aw1 : Aw0;
    const unsigned short* Bc = cur ? Bw1 : Bw0;
    const int kA = (j + 1) * 64, kC = (j + 2) * 64;
    short8 aF[2][4], bL[2][2], bH[2][2];

    // ---- phase A: quadrant (mi 0-3) x (ni 0-1); stage A1(j+1)->nxt ----
#pragma unroll
    for (int mi = 0; mi < 4; ++mi) {
      aF[0][mi] = *(const short8*)(Ac + mi * 1024 + fb + co0);
      aF[1][mi] = *(const short8*)(Ac + mi * 1024 + fb + co1);
    }
#pragma unroll
    for (int ni = 0; ni < 2; ++ni) {
      bL[0][ni] = *(const short8*)(Bc + ni * 1024 + fb + co0);
      bL[1][ni] = *(const short8*)(Bc + ni * 1024 + fb + co1);
    }
    if (j + 1 < QNT) STAGE_A(nxt, 1, kA);
    __builtin_amdgcn_s_barrier();
    asm volatile("s_waitcnt lgkmcnt(0)" ::: "memory");
    __builtin_amdgcn_s_setprio(1);
#pragma unroll
    for (int ks = 0; ks < 2; ++ks)
#pragma unroll
      for (int mi = 0; mi < 4; ++mi)
#pragma unroll
        for (int ni = 0; ni < 2; ++ni)
          acc[mi][ni] = __builtin_amdgcn_mfma_f32_16x16x32_bf16(
              bL[ks][ni], aF[ks][mi], acc[mi][ni], 0, 0, 0);
    __builtin_amdgcn_s_setprio(0);
    __builtin_amdgcn_s_barrier();

    // ---- phase B: (mi 0-3) x (ni 2-3); stage B1(j+1)->nxt ----
#pragma unroll
    for (int ni = 0; ni < 2; ++ni) {
      bH[0][ni] = *(const short8*)(Bc + (ni + 2) * 1024 + fb + co0);
      bH[1][ni] = *(const short8*)(Bc + (ni + 2) * 1024 + fb + co1);
    }
    if (j + 1 < QNT) STAGE_B(nxt, 1, kA);
    __builtin_amdgcn_s_barrier();
    asm volatile("s_waitcnt lgkmcnt(0)" ::: "memory");
    __builtin_amdgcn_s_setprio(1);
#pragma unroll
    for (int ks = 0; ks < 2; ++ks)
#pragma unroll
      for (int mi = 0; mi < 4; ++mi)
#pragma unroll
        for (int ni = 0; ni < 2; ++ni)
          acc[mi][ni + 2] = __builtin_amdgcn_mfma_f32_16x16x32_bf16(
              bH[ks][ni], aF[ks][mi], acc[mi][ni + 2], 0, 0, 0);
    __builtin_amdgcn_s_setprio(0);
    __builtin_amdgcn_s_barrier();

    // ---- phase C: (mi 4-7) x (ni 0-1); stage B0(j+2)->cur (dead after B) --
#pragma unroll
    for (int mi = 0; mi < 4; ++mi) {
      aF[0][mi] = *(const short8*)(Ac + (mi + 4) * 1024 + fb + co0);
      aF[1][mi] = *(const short8*)(Ac + (mi + 4) * 1024 + fb + co1);
    }
    if (j + 2 < QNT) STAGE_B(cur, 0, kC);
    __builtin_amdgcn_s_barrier();
    asm volatile("s_waitcnt lgkmcnt(0)" ::: "memory");
    __builtin_amdgcn_s_setprio(1);
#pragma unroll
    for (int ks = 0; ks < 2; ++ks)
#pragma unroll
      for (int mi = 0; mi < 4; ++mi)
#pragma unroll
        for (int ni = 0; ni < 2; ++ni)
          acc[mi + 4][ni] = __builtin_amdgcn_mfma_f32_16x16x32_bf16(
              bL[ks][ni], aF[ks][mi], acc[mi + 4][ni], 0, 0, 0);
    __builtin_amdgcn_s_setprio(0);
    __builtin_amdgcn_s_barrier();

    // ---- phase D: (mi 4-7) x (ni 2-3); stage A0(j+2)->cur (dead after C);
    //      counted vmcnt: keep 2 half-tiles (4 loads) in flight ----
    if (j + 2 < QNT) {
      STAGE_A(cur, 0, kC);
      asm volatile("s_waitcnt vmcnt(4)" ::: "memory");  // tile j+1 landed
    } else {
      asm volatile("s_waitcnt vmcnt(0)" ::: "memory");  // tail drain
    }
    __builtin_amdgcn_s_barrier();
    __builtin_amdgcn_s_setprio(1);
#pragma unroll
    for (int ks = 0; ks < 2; ++ks)
#pragma unroll
      for (int mi = 0; mi < 4; ++mi)
#pragma unroll
        for (int ni = 0; ni < 2; ++ni)
          acc[mi + 4][ni + 2] = __builtin_amdgcn_mfma_f32_16x16x32_bf16(
              bH[ks][ni], aF[ks][mi], acc[mi + 4][ni + 2], 0, 0, 0);
    __builtin_amdgcn_s_setprio(0);
    __builtin_amdgcn_s_barrier();
  }
#undef STAGE_A
#undef STAGE_B

  // epilogue: m = m0+wr*128+mi*16+l15, n = n0+wc*64+ni*16+quad*4+r
  const int which = n0 >> 10;                      // block-uniform: q/k/v
  if (which < 2) {
    unsigned short* dst = (which == 0) ? Oq : Ok;
    const float sc = (which == 0) ? Q_PRESCALE : 1.0f;
#pragma unroll
    for (int ni = 0; ni < 4; ++ni) {
      const int n = n0 + wc * 64 + ni * 16 + quad * 4;
      const int h = (n >> 6) & (NH - 1), d = n & (HD - 1);
#pragma unroll
      for (int mi = 0; mi < 8; ++mi) {
        const int m = m0 + wr * 128 + mi * 16 + l15;
        const int b = m >> 11, t = m & (T_SEQ - 1);
        ushort4 pk;
        pk.x = f2bf(acc[mi][ni][0] * sc); pk.y = f2bf(acc[mi][ni][1] * sc);
        pk.z = f2bf(acc[mi][ni][2] * sc); pk.w = f2bf(acc[mi][ni][3] * sc);
        *(ushort4*)(dst + (((size_t)(b * NH + h) * T_SEQ + t) << 6) + d) = pk;
      }
    }
  } else {
#pragma unroll
    for (int ni = 0; ni < 4; ++ni) {
      const int nb = n0 + wc * 64 + ni * 16 + quad * 4;
      const int h = (nb >> 6) & (NH - 1);
#pragma unroll
      for (int mi = 0; mi < 8; ++mi) {
        const int m = m0 + wr * 128 + mi * 16 + l15;
        const int b = m >> 11, t = m & (T_SEQ - 1);
#pragma unroll
        for (int r = 0; r < 4; ++r) {
          const int d = (nb + r) & (HD - 1);
          Ovt[((size_t)((b * NH + h) * HD + d) << 11) + t] = f2bf(acc[mi][ni][r]);
        }
      }
    }
  }
}

// ===== 128x128 / BK=64, 4-wave, 1-barrier-per-K-tile proj GEMM (R11 best) ==
// REVERTED from B-global (R13: 95us, gather-uncoalesced B reads) to the
// measured-best LDS-staged form (R11: total 246.8). Three LDS schedules tie
// ~75us; global-B strictly worse -> proj parked at this structure.
__global__ __launch_bounds__(256, 2) void gemm_bf16_proj128(
    const unsigned short* __restrict__ A,   // [M,K] bf16 (attn out)
    const unsigned short* __restrict__ B,   // [N,K] bf16 (Wproj)
    float* __restrict__ O,                  // [M,N] fp32
    const int K)
{
  __shared__ __align__(16) unsigned short As[2][128 * 64];  // 32 KiB
  __shared__ __align__(16) unsigned short Bs[3][128 * 64];  // 48 KiB
  const int tid = threadIdx.x;
  const int w = tid >> 6, l = tid & 63;
  const int quad = l >> 4, l15 = l & 15;
  const int wr = w >> 1, wc = w & 1;               // 2M x 2N wave grid
  const int lin = blockIdx.y * 8 + blockIdx.x;
  const int swz = (lin & 7) * 64 + (lin >> 3);     // bijective, 512%8==0
  const int m0 = (swz >> 3) * 128, n0 = (swz & 7) * 128;

  // staging: 256 threads cover one 32-row chunk (4 KiB) per gl2lds16.
  const int st_row = tid >> 3;                     // 0..31
  const int st_sch = ((tid & 7) ^ (st_row & 7)) * 8;
  const unsigned short* Ast = A + (size_t)(m0 + st_row) * K + st_sch;
  const unsigned short* Bst = B + (size_t)(n0 + st_row) * K + st_sch;
  const int dst8 = tid * 8;

#define PSTG_A(buf, kof) do { \
    gl2lds16(Ast + (kof), &As[buf][dst8]); \
    gl2lds16(Ast + (size_t)32 * K + (kof), &As[buf][2048 + dst8]); \
    gl2lds16(Ast + (size_t)64 * K + (kof), &As[buf][4096 + dst8]); \
    gl2lds16(Ast + (size_t)96 * K + (kof), &As[buf][6144 + dst8]); } while (0)
#define PSTG_B(buf, kof) do { \
    gl2lds16(Bst + (kof), &Bs[buf][dst8]); \
    gl2lds16(Bst + (size_t)32 * K + (kof), &Bs[buf][2048 + dst8]); \
    gl2lds16(Bst + (size_t)64 * K + (kof), &Bs[buf][4096 + dst8]); \
    gl2lds16(Bst + (size_t)96 * K + (kof), &Bs[buf][6144 + dst8]); } while (0)

  // fragment reads: row = {wr|wc}*64 + idx*16 + l15; chunk = (ks*4+quad)^(l15&7)
  const int sw7 = l15 & 7;
  const int co0 = (quad ^ sw7) * 8;
  const int co1 = co0 ^ 32;
  const unsigned short* Aw0 = &As[0][wr * 4096 + l15 * 64];
  const unsigned short* Aw1 = &As[1][wr * 4096 + l15 * 64];
  const unsigned short* Bw0 = &Bs[0][wc * 4096 + l15 * 64];
  const unsigned short* Bw1 = &Bs[1][wc * 4096 + l15 * 64];
  const unsigned short* Bw2 = &Bs[2][wc * 4096 + l15 * 64];

  floatx4 acc[4][4];
#pragma unroll
  for (int mi = 0; mi < 4; ++mi)
#pragma unroll
    for (int ni = 0; ni < 4; ++ni) acc[mi][ni] = (floatx4){0.f, 0.f, 0.f, 0.f};

  // prologue: A(0)->A0, B(0)->B0, B(1)->B1 (12 loads); vmcnt(4): tile0 landed
  PSTG_A(0, 0); PSTG_B(0, 0); PSTG_B(1, 64);
  asm volatile("s_waitcnt vmcnt(4)" ::: "memory");
  __builtin_amdgcn_s_barrier();

  int jm3 = 0;   // j % 3 (B buffer index)
#pragma unroll 1
  for (int j = 0; j < QNT; ++j) {
    const int cur = j & 1, nxt = cur ^ 1;
    const unsigned short* Ac = cur ? Aw1 : Aw0;
    const unsigned short* Bc = (jm3 == 0) ? Bw0 : (jm3 == 1) ? Bw1 : Bw2;
    const int tb = (jm3 >= 1) ? jm3 - 1 : 2;       // (j+2) % 3
    short8 aF[2][4], bL[2][2], bH[2][2];

    // ---- P-A: read ALL frags of tile j; stage A(j+1); MFMA ni0-1 ----
#pragma unroll
    for (int mi = 0; mi < 4; ++mi) {
      aF[0][mi] = *(const short8*)(Ac + mi * 1024 + co0);
      aF[1][mi] = *(const short8*)(Ac + mi * 1024 + co1);
    }
#pragma unroll
    for (int ni = 0; ni < 2; ++ni) {
      bL[0][ni] = *(const short8*)(Bc + ni * 1024 + co0);
      bL[1][ni] = *(const short8*)(Bc + ni * 1024 + co1);
      bH[0][ni] = *(const short8*)(Bc + (ni + 2) * 1024 + co0);
      bH[1][ni] = *(const short8*)(Bc + (ni + 2) * 1024 + co1);
    }
    if (j + 1 < QNT) PSTG_A(nxt, (j + 1) * 64);
    asm volatile("s_waitcnt lgkmcnt(0)" ::: "memory");
    __builtin_amdgcn_s_setprio(1);
#pragma unroll
    for (int ks = 0; ks < 2; ++ks)
#pragma unroll
      for (int mi = 0; mi < 4; ++mi)
#pragma unroll
        for (int ni = 0; ni < 2; ++ni)
          acc[mi][ni] = __builtin_amdgcn_mfma_f32_16x16x32_bf16(
              bL[ks][ni], aF[ks][mi], acc[mi][ni], 0, 0, 0);
    __builtin_amdgcn_s_setprio(0);

    // ---- P-B: stage B(j+2); MFMA ni2-3; counted vmcnt; ONE barrier ----
    if (j + 2 < QNT) PSTG_B(tb, (j + 2) * 64);
    __builtin_amdgcn_s_setprio(1);
#pragma unroll
    for (int ks = 0; ks < 2; ++ks)
#pragma unroll
      for (int mi = 0; mi < 4; ++mi)
#pragma unroll
        for (int ni = 0; ni < 2; ++ni)
          acc[mi][ni + 2] = __builtin_amdgcn_mfma_f32_16x16x32_bf16(
              bH[ks][ni], aF[ks][mi], acc[mi][ni + 2], 0, 0, 0);
    __builtin_amdgcn_s_setprio(0);
    if (j + 2 < QNT) asm volatile("s_waitcnt vmcnt(4)" ::: "memory");
    else             asm volatile("s_waitcnt vmcnt(0)" ::: "memory");
    __builtin_amdgcn_s_barrier();
    jm3 = (jm3 == 2) ? 0 : jm3 + 1;
  }
#undef PSTG_A
#undef PSTG_B

  // epilogue: m = m0+wr*64+mi*16+l15, n = n0+wc*64+ni*16+quad*4+r (fp32x4)
#pragma unroll
  for (int ni = 0; ni < 4; ++ni) {
    const int n = n0 + wc * 64 + ni * 16 + quad * 4;
#pragma unroll
    for (int mi = 0; mi < 4; ++mi) {
      const int m = m0 + wr * 64 + mi * 16 + l15;
      *(float4*)(O + (size_t)m * CDIM + n) =
          make_float4(acc[mi][ni][0], acc[mi][ni][1], acc[mi][ni][2], acc[mi][ni][3]);
    }
  }
}

// ======== Flash attention v6 + T5 setprio around MFMA clusters ========
// v6 structure (best measured ~71.6us); NEW: s_setprio(1) around the QK^T
// and PV MFMA groups. 2 blocks/CU -> waves at different kt phases compete
// (R7 PMC: VALU 41% vs MFMA 18%); prio lets MFMA-issuing waves win
// arbitration (catalog T5: attn +4-7%, m191).
#define TK 64
#define PTP 72     // Pt pitch (2-way max on writes = free)

__global__ __launch_bounds__(512) void attn_mfma(
    const unsigned short* __restrict__ Q,
    const unsigned short* __restrict__ K,
    const unsigned short* __restrict__ Vt,
    unsigned short* __restrict__ O)
{
  __shared__ unsigned short Ks[2][TK * HD];     // swizzled, 2x8 KB
  __shared__ unsigned short Vts[2][HD * TK];    // swizzled, 2x8 KB
  __shared__ unsigned short Pt[8][16 * PTP];    // per-wave P^T (18.4 KB)
  const int tid = threadIdx.x;
  const int w = tid >> 6, l = tid & 63;         // 8 waves
  const int quad = l >> 4, l15 = l & 15;
  const int drow = 8 * w + (l >> 3);
  const int dch = ((l & 7) ^ (l >> 3)) * 8;     // XOR-swizzled source chunk
  const int sw7 = l15 & 7;

  const int bh = blockIdx.x & 63;
  const int pp = blockIdx.x >> 6;               // 0..7
  const int b = bh >> 4, h = bh & 15;
  const size_t hoff = (size_t)bh * T_SEQ * HD;
  const unsigned short* Qh = Q + hoff;
  const unsigned short* Kdma = K + hoff + (size_t)drow * HD + dch;
  const unsigned short* Vdma = Vt + hoff + ((size_t)drow << 11) + dch;
  const int wb = w * 512;                       // wave's LDS slice (ushorts)

  short8 ones;
#pragma unroll
  for (int j = 0; j < 8; ++j) ones[j] = (short)0x3F80;  // bf16 1.0

#pragma unroll 1
  for (int ii = 0; ii < 2; ++ii) {
    const int qtile = ii ? pp : (15 - pp);      // heavy first
    const int qw = qtile * 128 + w * 16;

    short8 qf[2];
    {
      const int qrow = qw + l15;
      qf[0] = *(const short8*)(Qh + (size_t)qrow * HD + quad * 8);
      qf[1] = *(const short8*)(Qh + (size_t)qrow * HD + 32 + quad * 8);
    }

    floatx4 Of[4];
#pragma unroll
    for (int dc = 0; dc < 4; ++dc) Of[dc] = (floatx4){0.f, 0.f, 0.f, 0.f};
    floatx4 lacc = (floatx4){0.f, 0.f, 0.f, 0.f};

    const int nkt = 2 * qtile + 2;
    __syncthreads();                  // (ii=1) prior reads of buf0 done
    gl2lds16(Kdma, &Ks[0][wb]);       // prologue: tile 0 -> buf0
    gl2lds16(Vdma, &Vts[0][wb]);

    for (int kt = 0; kt < nkt; ++kt) {
      const int kt0 = kt * TK;
      const int cur = kt & 1, nxt = 1 - cur;
      __syncthreads();                // drains DMA kt; buf[nxt] reads done
      if (kt + 1 < nkt) {             // DMA kt+1 overlaps compute of kt
        gl2lds16(Kdma + (size_t)(kt0 + TK) * HD, &Ks[nxt][wb]);
        gl2lds16(Vdma + kt0 + TK, &Vts[nxt][wb]);
      }

      if (qw + 15 >= kt0) {           // wave-uniform: skip fully-masked tiles
        // --- S^T = K Q^T ---
        floatx4 Sf[4];
        __builtin_amdgcn_s_setprio(1);
#pragma unroll
        for (int cb = 0; cb < 4; ++cb) {
          Sf[cb] = (floatx4){0.f, 0.f, 0.f, 0.f};
          const int krow = cb * 16 + l15;
#pragma unroll
          for (int h2 = 0; h2 < 2; ++h2) {
            const int ch = (h2 * 4 + quad) ^ sw7;
            const short8 kf = *(const short8*)&Ks[cur][krow * 64 + ch * 8];
            Sf[cb] = __builtin_amdgcn_mfma_f32_16x16x32_bf16(kf, qf[h2], Sf[cb], 0, 0, 0);
          }
        }
        __builtin_amdgcn_s_setprio(0);
        // --- p = exp2(s); lane's 16 values all for q = qw+l15 ---
        const bool full = (kt0 + 63 <= qw);
        const int q = qw + l15;
#pragma unroll
        for (int cb = 0; cb < 4; ++cb) {
          const int key0 = kt0 + cb * 16 + quad * 4;
          ushort4 pk;
          if (full) {
            pk.x = f2bf_trunc(exp2f(Sf[cb][0]));
            pk.y = f2bf_trunc(exp2f(Sf[cb][1]));
            pk.z = f2bf_trunc(exp2f(Sf[cb][2]));
            pk.w = f2bf_trunc(exp2f(Sf[cb][3]));
          } else {
            pk.x = (key0 + 0 > q) ? 0 : f2bf_trunc(exp2f(Sf[cb][0]));
            pk.y = (key0 + 1 > q) ? 0 : f2bf_trunc(exp2f(Sf[cb][1]));
            pk.z = (key0 + 2 > q) ? 0 : f2bf_trunc(exp2f(Sf[cb][2]));
            pk.w = (key0 + 3 > q) ? 0 : f2bf_trunc(exp2f(Sf[cb][3]));
          }
          *(ushort4*)&Pt[w][l15 * PTP + cb * 16 + quad * 4] = pk;
        }
        // --- O^T += V^T P^T ; l += 1^T P^T ---
        __builtin_amdgcn_s_setprio(1);
#pragma unroll
        for (int kg = 0; kg < 2; ++kg) {
          const short8 ptf = *(const short8*)&Pt[w][l15 * PTP + kg * 32 + quad * 8];
          lacc = __builtin_amdgcn_mfma_f32_16x16x32_bf16(ones, ptf, lacc, 0, 0, 0);
#pragma unroll
          for (int dc = 0; dc < 4; ++dc) {
            const int vrow = dc * 16 + l15;
            const int ch = (kg * 4 + quad) ^ sw7;
            const short8 vf = *(const short8*)&Vts[cur][vrow * 64 + ch * 8];
            Of[dc] = __builtin_amdgcn_mfma_f32_16x16x32_bf16(vf, ptf, Of[dc], 0, 0, 0);
          }
        }
        __builtin_amdgcn_s_setprio(0);
      }
    }

    // epilogue: lane owns token q = qw+l15; d = dc*16+quad*4+{0..3}
    const float inv = 1.f / lacc[0];
    const int q = qw + l15;
    unsigned short* orow = O + (size_t)(b * T_SEQ + q) * CDIM + h * HD + quad * 4;
#pragma unroll
    for (int dc = 0; dc < 4; ++dc) {
      ushort4 ov;
      ov.x = f2bf(Of[dc][0] * inv); ov.y = f2bf(Of[dc][1] * inv);
      ov.z = f2bf(Of[dc][2] * inv); ov.w = f2bf(Of[dc][3] * inv);
      *(ushort4*)(orow + dc * 16) = ov;
    }
  }
}

extern "C" void kernel_launch(void* const* d_in, const int* in_sizes, int n_in,
                              void* d_out, int out_size, void* d_ws, size_t ws_size,
                              hipStream_t stream) {
  const float* x     = (const float*)d_in[0];  // [B,T,C]
  const float* Wqkv  = (const float*)d_in[1];  // [3C,C]
  const float* Wproj = (const float*)d_in[2];  // [C,C]
  float* out = (float*)d_out;                  // [B,T,C] fp32

  const size_t XSZ = (size_t)MROWS * CDIM;          // 8388608
  const size_t WQSZ = (size_t)3 * CDIM * CDIM;      // 3145728
  const size_t WPSZ = (size_t)CDIM * CDIM;          // 1048576
  unsigned short* xb  = (unsigned short*)d_ws;      // bf16 x
  unsigned short* wqb = xb + XSZ;                   // bf16 Wqkv
  unsigned short* wpb = wqb + WQSZ;                 // bf16 Wproj
  unsigned short* qbuf = wpb + WPSZ;                // bf16 [B,H,T,D] (pre-scaled)
  unsigned short* kbuf = qbuf + XSZ;
  unsigned short* vtbuf = kbuf + XSZ;               // bf16 [B,H,D,T]
  unsigned short* abuf = vtbuf + XSZ;               // bf16 [B,T,C]

  // 0) fused casts to bf16 (xb|wqb|wpb contiguous)
  cast3_bf16<<<(X4 + WQ4 + WP4) / 256, 256, 0, stream>>>(x, Wqkv, Wproj, xb);

  // 1) QKV projection: R3 4-phase schedule + XCD swizzle
  dim3 g1(3 * CDIM / 256, MROWS / 256);   // (12,32)
  gemm_bf16_qkv256<<<g1, 512, 0, stream>>>(xb, wqb, qbuf, kbuf, vtbuf, CDIM);

  // 2) flash attention v6 + setprio
  attn_mfma<<<512, 512, 0, stream>>>(qbuf, kbuf, vtbuf, abuf);

  // 3) output projection: 128x128 1-barrier/K-tile (R11 best)
  dim3 g3(CDIM / 128, MROWS / 128);       // (8,64)
  gemm_bf16_proj128<<<g3, 256, 0, stream>>>(abuf, wpb, out, CDIM);
}